// Round 4
// baseline (250.496 us; speedup 1.0000x reference)
//
#include <hip/hip_runtime.h>
#include <hip/hip_bf16.h>

#define DIN 768
#define DD  64
#define NB  8
#define SS  2048
#define NROWS (NB*SS)   // 16384

typedef __bf16 bf16;
typedef __attribute__((ext_vector_type(8))) __bf16 bf16x8;
typedef __attribute__((ext_vector_type(4))) __bf16 bf16x4;
typedef __attribute__((ext_vector_type(4))) float f32x4;

#define MFMA16 __builtin_amdgcn_mfma_f32_16x16x32_bf16

// ---------------------------------------------------------------------------
// ws layout (bf16 elements):
//   wt : [3][64][768]   qn : [16384][64]   kn : [16384][64]   vT : [8][64][2048]
// ---------------------------------------------------------------------------

// Transpose + convert W [768][64] f32 -> Wt [64][768] bf16 (coalesced both sides).
__global__ __launch_bounds__(256) void k_wt(const float* __restrict__ Wq,
                                            const float* __restrict__ Wk,
                                            const float* __restrict__ Wv,
                                            bf16* __restrict__ wt)
{
    int t = blockIdx.y;
    const float* W = (t == 0) ? Wq : ((t == 1) ? Wk : Wv);
    bf16* o = wt + (size_t)t * DD * DIN;
    int k0 = blockIdx.x * 64;

    __shared__ float tile[64][65];

    #pragma unroll
    for (int i = 0; i < 4; ++i) {
        int idx = threadIdx.x + i * 256;
        int row = idx >> 4;
        int c4  = (idx & 15) * 4;
        f32x4 u = *(const f32x4*)(W + (size_t)(k0 + row) * DD + c4);
        tile[c4 + 0][row] = u[0]; tile[c4 + 1][row] = u[1];
        tile[c4 + 2][row] = u[2]; tile[c4 + 3][row] = u[3];
    }
    __syncthreads();
    #pragma unroll
    for (int i = 0; i < 4; ++i) {
        int idx = threadIdx.x + i * 256;
        int col = idx >> 4;
        int k4  = (idx & 15) * 4;
        bf16x4 u;
        u[0] = (bf16)tile[col][k4 + 0]; u[1] = (bf16)tile[col][k4 + 1];
        u[2] = (bf16)tile[col][k4 + 2]; u[3] = (bf16)tile[col][k4 + 3];
        *(bf16x4*)(o + (size_t)col * DIN + k0 + k4) = u;
    }
}

// Projection with explicit depth-3 register pipeline (latency-bound fix:
// R2 showed MfmaUtil 2.4 / VALUBusy 2.6 / 1.2 TB/s -> nothing in flight).
__global__ __launch_bounds__(256) void k_proj(
    const float* __restrict__ Xq, const float* __restrict__ Xk, const float* __restrict__ Xv,
    const float* __restrict__ bq, const float* __restrict__ bk, const float* __restrict__ bv,
    const bf16* __restrict__ wt,
    bf16* __restrict__ qn, bf16* __restrict__ kn, bf16* __restrict__ vT)
{
    int t = blockIdx.y;
    const float* X    = (t == 0) ? Xq : ((t == 1) ? Xk : Xv);
    const float* bias = (t == 0) ? bq : ((t == 1) ? bk : bv);
    const bf16*  w    = wt + (size_t)t * DD * DIN;

    int row0 = blockIdx.x * 64;
    int lane = threadIdx.x & 63;
    int wid  = threadIdx.x >> 6;
    int lr = lane & 15, lk = lane >> 4;
    int r  = row0 + wid * 16 + lr;

    const float* xp = X + (size_t)r * DIN + lk * 8;
    const bf16*  wp = w + (size_t)lr * DIN + lk * 8;

    f32x4 acc[4] = {};

    // depth-3 pipeline: slots hold X (2 x f32x4) and W (4 x bf16x8) per k-step
    f32x4  px0[3], px1[3];
    bf16x8 pw[3][4];
    #pragma unroll
    for (int p = 0; p < 3; ++p) {
        int kk = p * 32;
        px0[p] = *(const f32x4*)(xp + kk);
        px1[p] = *(const f32x4*)(xp + kk + 4);
        #pragma unroll
        for (int cf = 0; cf < 4; ++cf)
            pw[p][cf] = *(const bf16x8*)(wp + (size_t)cf * 16 * DIN + kk);
    }

    #pragma unroll
    for (int it = 0; it < 24; ++it) {
        const int slot = it % 3;             // static after full unroll
        bf16x8 a;
        a[0] = (bf16)px0[slot][0]; a[1] = (bf16)px0[slot][1];
        a[2] = (bf16)px0[slot][2]; a[3] = (bf16)px0[slot][3];
        a[4] = (bf16)px1[slot][0]; a[5] = (bf16)px1[slot][1];
        a[6] = (bf16)px1[slot][2]; a[7] = (bf16)px1[slot][3];
        bf16x8 w0 = pw[slot][0], w1 = pw[slot][1], w2 = pw[slot][2], w3 = pw[slot][3];
        if (it + 3 < 24) {                   // prefetch it+3 into this slot
            int kk = (it + 3) * 32;
            px0[slot] = *(const f32x4*)(xp + kk);
            px1[slot] = *(const f32x4*)(xp + kk + 4);
            #pragma unroll
            for (int cf = 0; cf < 4; ++cf)
                pw[slot][cf] = *(const bf16x8*)(wp + (size_t)cf * 16 * DIN + kk);
        }
        acc[0] = MFMA16(a, w0, acc[0], 0, 0, 0);
        acc[1] = MFMA16(a, w1, acc[1], 0, 0, 0);
        acc[2] = MFMA16(a, w2, acc[2], 0, 0, 0);
        acc[3] = MFMA16(a, w3, acc[3], 0, 0, 0);
    }

    #pragma unroll
    for (int cf = 0; cf < 4; ++cf) {
        float bc = bias[cf * 16 + lr];
        acc[cf][0] += bc; acc[cf][1] += bc; acc[cf][2] += bc; acc[cf][3] += bc;
    }

    if (t < 2) {
        const float c = (t == 0) ? 0.18033688011112042f /* log2(e)/8 */ : 1.0f;
        f32x4 ss = {};
        #pragma unroll
        for (int cf = 0; cf < 4; ++cf)
            #pragma unroll
            for (int reg = 0; reg < 4; ++reg)
                ss[reg] += acc[cf][reg] * acc[cf][reg];
        #pragma unroll
        for (int reg = 0; reg < 4; ++reg) {
            float v = ss[reg];
            v += __shfl_xor(v, 1); v += __shfl_xor(v, 2);
            v += __shfl_xor(v, 4); v += __shfl_xor(v, 8);
            ss[reg] = v;
        }
        bf16* o = (t == 0) ? qn : kn;
        #pragma unroll
        for (int reg = 0; reg < 4; ++reg) {
            float sc = __builtin_amdgcn_rsqf(ss[reg]) * c;
            int rr = row0 + wid * 16 + lk * 4 + reg;
            #pragma unroll
            for (int cf = 0; cf < 4; ++cf)
                o[(size_t)rr * DD + cf * 16 + lr] = (bf16)(acc[cf][reg] * sc);
        }
    } else {
        __shared__ bf16 vt[64][72];
        #pragma unroll
        for (int reg = 0; reg < 4; ++reg)
            #pragma unroll
            for (int cf = 0; cf < 4; ++cf)
                vt[cf * 16 + lr][wid * 16 + lk * 4 + reg] = (bf16)acc[cf][reg];
        __syncthreads();
        int bb = row0 >> 11, s0 = row0 & (SS - 1);
        #pragma unroll
        for (int j = 0; j < 4; ++j) {
            int f4 = threadIdx.x + j * 256;
            int dv = f4 >> 4, s4 = f4 & 15;
            bf16x4 u;
            u[0] = vt[dv][s4 * 4 + 0]; u[1] = vt[dv][s4 * 4 + 1];
            u[2] = vt[dv][s4 * 4 + 2]; u[3] = vt[dv][s4 * 4 + 3];
            *(bf16x4*)(vT + ((size_t)(bb * DD + dv)) * SS + s0 + s4 * 4) = u;
        }
    }
}

// Attention: 16 q-rows per block (grid 1024 -> 4 blocks/CU), 4 waves own S/4 each.
// LDS: P-transpose buffer aliases the (later-used) num-reduction buffer
// (both wave-private, disjoint lifetimes) -> 17.7 KB total, 16 waves/CU.
__global__ __launch_bounds__(256) void k_attn(
    const bf16* __restrict__ qn, const bf16* __restrict__ kn,
    const bf16* __restrict__ vT, float* __restrict__ out)
{
    int b  = blockIdx.y;
    int q0 = blockIdx.x * 16;
    int lane = threadIdx.x & 63, wid = threadIdx.x >> 6;
    int lr = lane & 15, lk = lane >> 4;

    __shared__ float num_all[4][16][68];     // 17.4 KiB; first 2 KiB/wave doubles as p_lds
    __shared__ float den_lds[4][16];
    bf16* p_lds = (bf16*)&num_all[wid][0][0];
    float (*num_lds)[68] = num_all[wid];

    const bf16* qb = qn + ((size_t)(b * SS + q0 + lr)) * DD + lk * 8;
    bf16x8 qf0 = *(const bf16x8*)(qb);
    bf16x8 qf1 = *(const bf16x8*)(qb + 32);

    const bf16* kb = kn + (size_t)b * SS * DD;
    const bf16* vb = vT + (size_t)b * DD * SS;

    f32x4 oacc[4] = {};
    f32x4 den     = {};

    int sbeg = wid * (SS / 4);
    for (int s = sbeg; s < sbeg + SS / 4; s += 64) {
        // ---- QK^T: scores[16q][64s] ----
        f32x4 sacc[4] = {};
        #pragma unroll
        for (int cf = 0; cf < 4; ++cf) {
            const bf16* kp = kb + (size_t)(s + cf * 16 + lr) * DD + lk * 8;
            bf16x8 k0 = *(const bf16x8*)(kp);
            bf16x8 k1 = *(const bf16x8*)(kp + 32);
            sacc[cf] = MFMA16(qf0, k0, sacc[cf], 0, 0, 0);
            sacc[cf] = MFMA16(qf1, k1, sacc[cf], 0, 0, 0);
        }
        // ---- p = exp2(score); den += p; transpose via swizzled wave-private LDS ----
        #pragma unroll
        for (int reg = 0; reg < 4; ++reg) {
            int prow = lk * 4 + reg;
            int swz  = (prow & 7) << 4;
            #pragma unroll
            for (int cf = 0; cf < 4; ++cf) {
                float p = __builtin_amdgcn_exp2f(sacc[cf][reg]);
                den[reg] += p;
                *(bf16*)((char*)p_lds + prow * 128 + ((((cf * 16 + lr) * 2)) ^ swz)) = (bf16)p;
            }
        }
        __builtin_amdgcn_sched_barrier(0);   // keep DS reads after DS writes
        bf16x8 pf0, pf1;
        {
            int swz = (lr & 7) << 4;
            pf0 = *(const bf16x8*)((char*)p_lds + lr * 128 + (((lk * 8) * 2) ^ swz));
            pf1 = *(const bf16x8*)((char*)p_lds + lr * 128 + (((32 + lk * 8) * 2) ^ swz));
        }
        // ---- PV: out[16q][64dv] += P[16q][64s] @ V[64s][64dv] ----
        #pragma unroll
        for (int cf = 0; cf < 4; ++cf) {
            const bf16* vp = vb + (size_t)(cf * 16 + lr) * SS + s + lk * 8;
            bf16x8 v0 = *(const bf16x8*)(vp);
            bf16x8 v1 = *(const bf16x8*)(vp + 32);
            oacc[cf] = MFMA16(pf0, v0, oacc[cf], 0, 0, 0);
            oacc[cf] = MFMA16(pf1, v1, oacc[cf], 0, 0, 0);
        }
    }

    // ---- den lane-reduce + dump partials (num overwrites p_lds region: same wave, in-order) ----
    #pragma unroll
    for (int reg = 0; reg < 4; ++reg) {
        float d = den[reg];
        d += __shfl_xor(d, 1); d += __shfl_xor(d, 2);
        d += __shfl_xor(d, 4); d += __shfl_xor(d, 8);
        if (lr == 0) den_lds[wid][lk * 4 + reg] = d;
        #pragma unroll
        for (int cf = 0; cf < 4; ++cf)
            num_lds[lk * 4 + reg][cf * 16 + lr] = oacc[cf][reg];
    }
    __syncthreads();

    // ---- combine 4 wave-partials, divide, store ----
    float* ob = out + ((size_t)b * SS + q0) * DD;
    #pragma unroll
    for (int j = 0; j < 4; ++j) {
        int e = threadIdx.x + j * 256;       // 0..1023
        int q = e >> 6, dv = e & 63;
        float n = num_all[0][q][dv] + num_all[1][q][dv] + num_all[2][q][dv] + num_all[3][q][dv];
        float d = den_lds[0][q] + den_lds[1][q] + den_lds[2][q] + den_lds[3][q];
        ob[e] = n / d;
    }
}

extern "C" void kernel_launch(void* const* d_in, const int* in_sizes, int n_in,
                              void* d_out, int out_size, void* d_ws, size_t ws_size,
                              hipStream_t stream) {
    const float* Xq = (const float*)d_in[0];
    const float* Xk = (const float*)d_in[1];
    const float* Xv = (const float*)d_in[2];
    const float* Wq = (const float*)d_in[3];
    const float* bq = (const float*)d_in[4];
    const float* Wk = (const float*)d_in[5];
    const float* bk = (const float*)d_in[6];
    const float* Wv = (const float*)d_in[7];
    const float* bv = (const float*)d_in[8];

    bf16* ws = (bf16*)d_ws;
    bf16* wt = ws;
    bf16* qn = ws + 3 * DD * DIN;
    bf16* kn = qn + (size_t)NROWS * DD;
    bf16* vT = kn + (size_t)NROWS * DD;
    float* o = (float*)d_out;

    hipLaunchKernelGGL(k_wt,   dim3(12, 3),  dim3(256), 0, stream, Wq, Wk, Wv, wt);
    hipLaunchKernelGGL(k_proj, dim3(256, 3), dim3(256), 0, stream,
                       Xq, Xk, Xv, bq, bk, bv, wt, qn, kn, vT);
    hipLaunchKernelGGL(k_attn, dim3(128, 8), dim3(256), 0, stream, qn, kn, vT, o);
}